// Round 1
// baseline (1568.488 us; speedup 1.0000x reference)
//
#include <hip/hip_runtime.h>
#include <hip/hip_fp16.h>

#define Bc 8
#define Nc 512
#define INc 64
#define Hc 128
#define Ac 32
#define REDc 32
#define OUTc 3
#define Lc 3

__device__ __forceinline__ float tanh_fast(float x) {
    // tanh(x) = 1 - 2/(e^{2x}+1); saturates correctly for |x| large.
    float e = __expf(2.f * x);
    return 1.f - 2.f * __builtin_amdgcn_rcpf(e + 1.f);
}

// Y[m,n] = act( sum_k (X[m,k]*sc[b,k]) * W[n,k] + b[n] );  X: MxK row-major, W: Nout x K row-major.
// grid = M/TM blocks, 128 threads. Requires K<=128, Nout<=128, TM divides Nc.
template <int TM>
__global__ void gemm_tm(const float* __restrict__ X, const float* __restrict__ W,
                        const float* __restrict__ bias, float* __restrict__ Y,
                        int K, int Nout, int act, const float* __restrict__ scale) {
    __shared__ float xs[TM * 128];
    int m0 = blockIdx.x * TM;
    int t = threadIdx.x;
    const float* sc = scale ? scale + (size_t)(m0 / Nc) * K : nullptr;
    for (int idx = t; idx < TM * K; idx += 128) {
        float v = X[(size_t)m0 * K + idx];
        if (sc) v *= sc[idx % K];
        xs[idx] = v;
    }
    __syncthreads();
    if (t < Nout) {
        float acc[TM];
        float bv = bias ? bias[t] : 0.f;
#pragma unroll
        for (int r = 0; r < TM; ++r) acc[r] = bv;
        const float* w = W + (size_t)t * K;
        for (int k = 0; k < K; ++k) {
            float wv = w[k];
#pragma unroll
            for (int r = 0; r < TM; ++r) acc[r] = fmaf(xs[r * K + k], wv, acc[r]);
        }
#pragma unroll
        for (int r = 0; r < TM; ++r) {
            float v = acc[r];
            if (act) v = fmaxf(v, 0.f);
            Y[(size_t)(m0 + r) * Nout + t] = v;
        }
    }
}

// T[b,i,h] = (1+eps)*X[b,i,h] + sum_j A[b,i,j]*X[b,j,h]   (A binary-sparse: skip zeros)
__global__ void spmm_eps(const float* __restrict__ A, const float* __restrict__ X,
                         const float* __restrict__ eps_ptr, float* __restrict__ T) {
    int bi = blockIdx.x;          // b*Nc + i
    int b = bi >> 9;
    int h = threadIdx.x;          // 128
    __shared__ float arow[Nc];
    const float* Ar = A + (size_t)bi * Nc;
    for (int j = h; j < Nc; j += 128) arow[j] = Ar[j];
    __syncthreads();
    const float* Xb = X + (size_t)b * Nc * Hc;
    float acc = 0.f;
    for (int j = 0; j < Nc; ++j) {
        float a = arow[j];                 // wave-uniform -> no divergence
        if (a != 0.f) acc = fmaf(a, Xb[(size_t)j * Hc + h], acc);
    }
    float eps = eps_ptr[0];
    size_t o = (size_t)bi * Hc + h;
    T[o] = (1.f + eps) * X[o] + acc;
}

__global__ void topo_combine(const float* __restrict__ Xh, const float* __restrict__ hA,
                             const float* __restrict__ hAC, const float* __restrict__ theta,
                             float* __restrict__ Xp) {
    int idx = blockIdx.x * blockDim.x + threadIdx.x;
    if (idx >= Bc * Nc * Hc) return;
    int h = idx & (Hc - 1);
    Xp[idx] = Xh[idx] + tanh_fast(hA[idx] * theta[2 * h]) + tanh_fast(hAC[idx] * theta[2 * h + 1]);
}

// One block per (b,i): e-row in LDS (fp16), softmax, ctx & alpha@Xy, epilogue adds XA+XAC.
__global__ __launch_bounds__(256) void attn_fused(
    const float* __restrict__ ho, const float* __restrict__ h1,
    const float* __restrict__ Xy, const float* __restrict__ wphi,
    const float* __restrict__ we_w, const float* __restrict__ we_b,
    const float* __restrict__ XA, const float* __restrict__ XAC,
    float* __restrict__ Xbar) {
    int bi = blockIdx.x;
    int b = bi >> 9;
    int t = threadIdx.x;
    __shared__ __half es[Nc * 34];   // pad 34 -> conflict-light
    __shared__ float ss[Nc];
    __shared__ float red[256];
    __shared__ float hos[Ac], wps[Ac], ctxs[Ac];
    if (t < Ac) { hos[t] = ho[(size_t)bi * Ac + t]; wps[t] = wphi[t]; }
    __syncthreads();
    const float* h1b = h1 + (size_t)b * Nc * Ac;
    for (int j = t; j < Nc; j += 256) {
        const float* h1j = h1b + (size_t)j * Ac;
        float s = 0.f;
        __half* ej = es + j * 34;
#pragma unroll
        for (int k = 0; k < Ac; ++k) {
            float e = tanh_fast(hos[k] + h1j[k]);
            ej[k] = __float2half(e);
            s = fmaf(e, wps[k], s);
        }
        ss[j] = s;
    }
    __syncthreads();
    // softmax over j (max-sub, exp, sum)
    float m = -1e30f;
    for (int j = t; j < Nc; j += 256) m = fmaxf(m, ss[j]);
    red[t] = m;
    __syncthreads();
#pragma unroll
    for (int s2 = 128; s2 > 0; s2 >>= 1) {
        if (t < s2) red[t] = fmaxf(red[t], red[t + s2]);
        __syncthreads();
    }
    m = red[0];
    __syncthreads();
    float sum = 0.f;
    for (int j = t; j < Nc; j += 256) {
        float a = __expf(ss[j] - m);
        ss[j] = a;
        sum += a;
    }
    red[t] = sum;
    __syncthreads();
#pragma unroll
    for (int s2 = 128; s2 > 0; s2 >>= 1) {
        if (t < s2) red[t] += red[t + s2];
        __syncthreads();
    }
    float rinv = 1.f / red[0];
    __syncthreads();
    // ctx[k] = sum_j alpha_j * e[j,k]
    {
        int k = t & 31, g = t >> 5;
        float c = 0.f;
        for (int j = g; j < Nc; j += 8)
            c = fmaf(ss[j], __half2float(es[j * 34 + k]), c);
        red[t] = c;
    }
    __syncthreads();
    if (t < 32) {
        float c = 0.f;
#pragma unroll
        for (int g = 0; g < 8; ++g) c += red[g * 32 + t];
        ctxs[t] = c * rinv;
    }
    __syncthreads();
    // att[h] = sum_j alpha_j * Xy[b,j,h]
    float aacc = 0.f;
    {
        int hh = t & 127, g = t >> 7;
        const float* Xyb = Xy + (size_t)b * Nc * Hc;
        for (int j = g; j < Nc; j += 2)
            aacc = fmaf(ss[j], Xyb[(size_t)j * Hc + hh], aacc);
    }
    red[t] = aacc;
    __syncthreads();
    if (t < Hc) {
        float a = (red[t] + red[t + 128]) * rinv;
        float acc = we_b[t];
        const float* w = we_w + (size_t)t * Ac;
#pragma unroll
        for (int k = 0; k < Ac; ++k) acc = fmaf(ctxs[k], w[k], acc);
        size_t o = (size_t)bi * Hc + t;
        Xbar[o] = XA[o] + XAC[o] + a + acc;
    }
}

// grid = B, 128 threads: y2[b,h] = sigmoid(lin2(relu(lin1(sum_i Xbar))))
__global__ void se_kernel(const float* __restrict__ Xbar, const float* __restrict__ l1w,
                          const float* __restrict__ l1b, const float* __restrict__ l2w,
                          const float* __restrict__ l2b, float* __restrict__ y2) {
    int b = blockIdx.x;
    int t = threadIdx.x; // 128
    __shared__ float s[Hc];
    __shared__ float y1s[REDc];
    const float* Xb = Xbar + (size_t)b * Nc * Hc;
    float acc = 0.f;
    for (int i = 0; i < Nc; ++i) acc += Xb[(size_t)i * Hc + t];
    s[t] = acc;
    __syncthreads();
    if (t < REDc) {
        float a = l1b[t];
        const float* w = l1w + (size_t)t * Hc;
        for (int k = 0; k < Hc; ++k) a = fmaf(s[k], w[k], a);
        y1s[t] = fmaxf(a, 0.f);
    }
    __syncthreads();
    float a = l2b[t];
    const float* w2 = l2w + (size_t)t * REDc;
#pragma unroll
    for (int k = 0; k < REDc; ++k) a = fmaf(y1s[k], w2[k], a);
    y2[(size_t)b * Hc + t] = 1.f / (1.f + __expf(-a));
}

// grid = B*N, 64 threads: head1(relu) + head2 fused
__global__ void head_kernel(const float* __restrict__ Xp, const float* __restrict__ h1w,
                            const float* __restrict__ h1b, const float* __restrict__ h2w,
                            const float* __restrict__ h2b, float* __restrict__ out) {
    int m = blockIdx.x;
    int t = threadIdx.x; // 64
    __shared__ float xs[Hc];
    __shared__ float hs[64];
    xs[t] = Xp[(size_t)m * Hc + t];
    xs[t + 64] = Xp[(size_t)m * Hc + t + 64];
    __syncthreads();
    float a = h1b[t];
    const float* w = h1w + (size_t)t * Hc;
    for (int k = 0; k < Hc; ++k) a = fmaf(xs[k], w[k], a);
    hs[t] = fmaxf(a, 0.f);
    __syncthreads();
    if (t < OUTc) {
        float o = h2b[t];
        const float* w2 = h2w + (size_t)t * 64;
#pragma unroll
        for (int k = 0; k < 64; ++k) o = fmaf(hs[k], w2[k], o);
        out[(size_t)m * OUTc + t] = o;
    }
}

extern "C" void kernel_launch(void* const* d_in, const int* in_sizes, int n_in,
                              void* d_out, int out_size, void* d_ws, size_t ws_size,
                              hipStream_t stream) {
    const float* X       = (const float*)d_in[0];
    const float* A       = (const float*)d_in[1];
    const float* Acg     = (const float*)d_in[2];
    const float* embed_w = (const float*)d_in[3];
    const float* embed_b = (const float*)d_in[4];
    const float* topo_eps= (const float*)d_in[5];
    const float* topo_w  = (const float*)d_in[6];
    const float* topo_b  = (const float*)d_in[7];
    const float* theta   = (const float*)d_in[8];
    const float* gin_eps = (const float*)d_in[9];
    const float* gin_w   = (const float*)d_in[10];
    const float* gin_b   = (const float*)d_in[11];
    const float* wo      = (const float*)d_in[12];
    const float* w1      = (const float*)d_in[13];
    const float* wphi    = (const float*)d_in[14];
    const float* wy_w    = (const float*)d_in[15];
    const float* wy_b    = (const float*)d_in[16];
    const float* we_w    = (const float*)d_in[17];
    const float* we_b    = (const float*)d_in[18];
    const float* lin1_w  = (const float*)d_in[19];
    const float* lin1_b  = (const float*)d_in[20];
    const float* lin2_w  = (const float*)d_in[21];
    const float* lin2_b  = (const float*)d_in[22];
    const float* mlp_w   = (const float*)d_in[23];
    const float* mlp_b   = (const float*)d_in[24];
    const float* head1_w = (const float*)d_in[25];
    const float* head1_b = (const float*)d_in[26];
    const float* head2_w = (const float*)d_in[27];
    const float* head2_b = (const float*)d_in[28];
    float* out = (float*)d_out;

    float* ws = (float*)d_ws;
    const int MN = Bc * Nc;              // 4096
    const size_t SZ = (size_t)MN * Hc;   // 524288
    float* Xh   = ws;
    float* Xp   = Xh + SZ;
    float* T    = Xp + SZ;
    float* G1   = T + SZ;
    float* G2   = G1 + SZ;
    float* Xy   = G2 + SZ;
    float* Xbar = Xy + SZ;
    float* hov  = Xbar + SZ;             // MN*32
    float* h1v  = hov + (size_t)MN * Ac;
    float* y2   = h1v + (size_t)MN * Ac; // B*H

    // embed: Xh = X @ embed_w.T + b
    gemm_tm<8><<<MN / 8, 128, 0, stream>>>(X, embed_w, embed_b, Xh, INc, Hc, 0, nullptr);
    // topo GIN on A and Ac
    spmm_eps<<<MN, 128, 0, stream>>>(A, Xh, topo_eps, T);
    gemm_tm<8><<<MN / 8, 128, 0, stream>>>(T, topo_w, topo_b, G1, Hc, Hc, 1, nullptr);
    spmm_eps<<<MN, 128, 0, stream>>>(Acg, Xh, topo_eps, T);
    gemm_tm<8><<<MN / 8, 128, 0, stream>>>(T, topo_w, topo_b, G2, Hc, Hc, 1, nullptr);
    topo_combine<<<(MN * Hc + 255) / 256, 256, 0, stream>>>(Xh, G1, G2, theta, Xp);

    for (int l = 0; l < Lc; ++l) {
        spmm_eps<<<MN, 128, 0, stream>>>(A, Xp, gin_eps + l * 2 + 0, T);
        gemm_tm<8><<<MN / 8, 128, 0, stream>>>(T, gin_w + (size_t)(l * 2 + 0) * Hc * Hc,
                                               gin_b + (size_t)(l * 2 + 0) * Hc, G1, Hc, Hc, 1, nullptr);
        spmm_eps<<<MN, 128, 0, stream>>>(Acg, Xp, gin_eps + l * 2 + 1, T);
        gemm_tm<8><<<MN / 8, 128, 0, stream>>>(T, gin_w + (size_t)(l * 2 + 1) * Hc * Hc,
                                               gin_b + (size_t)(l * 2 + 1) * Hc, G2, Hc, Hc, 1, nullptr);
        gemm_tm<8><<<MN / 8, 128, 0, stream>>>(Xp, wo + (size_t)l * Ac * Hc, nullptr, hov, Hc, Ac, 0, nullptr);
        gemm_tm<8><<<MN / 8, 128, 0, stream>>>(Xp, w1 + (size_t)l * Ac * Hc, nullptr, h1v, Hc, Ac, 0, nullptr);
        gemm_tm<8><<<MN / 8, 128, 0, stream>>>(Xp, wy_w + (size_t)l * Hc * Hc, wy_b + (size_t)l * Hc, Xy, Hc, Hc, 0, nullptr);
        attn_fused<<<MN, 256, 0, stream>>>(hov, h1v, Xy, wphi + (size_t)l * Ac,
                                           we_w + (size_t)l * Hc * Ac, we_b + (size_t)l * Hc, G1, G2, Xbar);
        se_kernel<<<Bc, 128, 0, stream>>>(Xbar, lin1_w + (size_t)l * REDc * Hc, lin1_b + (size_t)l * REDc,
                                          lin2_w + (size_t)l * Hc * REDc, lin2_b + (size_t)l * Hc, y2);
        gemm_tm<8><<<MN / 8, 128, 0, stream>>>(Xbar, mlp_w + (size_t)l * Hc * Hc, mlp_b + (size_t)l * Hc, Xp, Hc, Hc, 0, y2);
    }
    head_kernel<<<MN, 64, 0, stream>>>(Xp, head1_w, head1_b, head2_w, head2_b, out);
}

// Round 2
// 763.638 us; speedup vs baseline: 2.0540x; 2.0540x over previous
//
#include <hip/hip_runtime.h>

#define Bc 8
#define Nc 512
#define INc 64
#define Hc 128
#define Atc 32
#define REDc 32
#define OUTc 3
#define Lc 3

__device__ __forceinline__ float tanh_fast(float x) {
    // tanh(x) = 1 - 2/(e^{2x}+1); saturates correctly for |x| large.
    float e = __expf(2.f * x);
    return 1.f - 2.f * __builtin_amdgcn_rcpf(e + 1.f);
}

// Y[m,n] = act( sum_k (X[m,k]*sc[b,k]) * W[n,k] + b[n] )
// X: MxK row-major, W: NOUT x K row-major. 128 threads, G=128/NOUT groups over rows.
template <int TM, int NOUT>
__global__ __launch_bounds__(128) void gemm_tm(
        const float* __restrict__ X, const float* __restrict__ W,
        const float* __restrict__ bias, float* __restrict__ Y,
        int K, int act, const float* __restrict__ scale) {
    constexpr int G = 128 / NOUT;
    constexpr int RPG = TM / G;
    __shared__ float xs[TM * 128];
    int m0 = blockIdx.x * TM;
    int t = threadIdx.x;
    const float* sc = scale ? scale + (size_t)(m0 >> 9) * K : nullptr;
    for (int idx = t; idx < TM * K; idx += 128) {
        float v = X[(size_t)m0 * K + idx];
        if (sc) v *= sc[idx % K];
        xs[idx] = v;
    }
    __syncthreads();
    int n = t % NOUT;
    int grp = t / NOUT;
    float bv = bias ? bias[n] : 0.f;
    float acc[RPG];
#pragma unroll
    for (int r = 0; r < RPG; ++r) acc[r] = bv;
    const float* w = W + (size_t)n * K;
    for (int k = 0; k < K; k += 4) {
        float4 wv = *(const float4*)(w + k);
#pragma unroll
        for (int r = 0; r < RPG; ++r) {
            float4 xv = *(const float4*)(xs + (grp * RPG + r) * K + k);
            acc[r] = fmaf(xv.x, wv.x, acc[r]);
            acc[r] = fmaf(xv.y, wv.y, acc[r]);
            acc[r] = fmaf(xv.z, wv.z, acc[r]);
            acc[r] = fmaf(xv.w, wv.w, acc[r]);
        }
    }
#pragma unroll
    for (int r = 0; r < RPG; ++r) {
        float v = acc[r];
        if (act) v = fmaxf(v, 0.f);
        Y[(size_t)(m0 + grp * RPG + r) * NOUT + n] = v;
    }
}

// T[b,i,h] = (1+eps)*X[b,i,h] + sum_j A[b,i,j]*X[b,j,h].  A binary: compact nonzeros first.
__global__ __launch_bounds__(128) void spmm_eps(const float* __restrict__ A, const float* __restrict__ X,
                         const float* __restrict__ eps_ptr, float* __restrict__ T) {
    int bi = blockIdx.x;          // b*Nc + i
    int b = bi >> 9;
    int h = threadIdx.x;          // 128
    __shared__ int idxs[Nc];
    __shared__ int cnt;
    if (h == 0) cnt = 0;
    __syncthreads();
    const float4* Ar4 = (const float4*)(A + (size_t)bi * Nc);
    float4 a4 = Ar4[h];           // j = 4h..4h+3
    if (a4.x != 0.f) idxs[atomicAdd(&cnt, 1)] = 4 * h + 0;
    if (a4.y != 0.f) idxs[atomicAdd(&cnt, 1)] = 4 * h + 1;
    if (a4.z != 0.f) idxs[atomicAdd(&cnt, 1)] = 4 * h + 2;
    if (a4.w != 0.f) idxs[atomicAdd(&cnt, 1)] = 4 * h + 3;
    __syncthreads();
    int n = cnt;
    const float* Xb = X + (size_t)b * Nc * Hc;
    float acc = 0.f;
    for (int q = 0; q < n; ++q) {
        int j = idxs[q];
        acc += Xb[(size_t)j * Hc + h];
    }
    float eps = eps_ptr[0];
    size_t o = (size_t)bi * Hc + h;
    T[o] = (1.f + eps) * X[o] + acc;
}

__global__ void topo_combine(const float* __restrict__ Xh, const float* __restrict__ hA,
                             const float* __restrict__ hAC, const float* __restrict__ theta,
                             float* __restrict__ Xp) {
    int idx = blockIdx.x * blockDim.x + threadIdx.x;
    if (idx >= Bc * Nc * Hc) return;
    int h = idx & (Hc - 1);
    Xp[idx] = Xh[idx] + tanh_fast(hA[idx] * theta[2 * h]) + tanh_fast(hAC[idx] * theta[2 * h + 1]);
}

// K1: S[b,i,j] = sum_k tanh(ho[b,i,k]+h1[b,j,k])*wphi[k].  grid = B*(N/8), 256 threads.
__global__ __launch_bounds__(256) void score_kernel(
        const float* __restrict__ ho, const float* __restrict__ h1,
        const float* __restrict__ wphi, float* __restrict__ S) {
    int blk = blockIdx.x;
    int b = blk >> 6;
    int i0 = (blk & 63) * 8;
    int t = threadIdx.x;
    __shared__ float hos[8 * 32];
    __shared__ float wps[32];
    if (t < 8 * 32) hos[t] = ho[((size_t)b * Nc + i0) * 32 + t];
    if (t < 32) wps[t] = wphi[t];
    __syncthreads();
    float wpr[32];
#pragma unroll
    for (int q = 0; q < 8; ++q) {
        float4 v = ((const float4*)wps)[q];
        wpr[4 * q] = v.x; wpr[4 * q + 1] = v.y; wpr[4 * q + 2] = v.z; wpr[4 * q + 3] = v.w;
    }
    for (int jj = 0; jj < 2; ++jj) {
        int j = t + jj * 256;
        const float4* h1j = (const float4*)(h1 + ((size_t)b * Nc + j) * 32);
        float h1r[32];
#pragma unroll
        for (int q = 0; q < 8; ++q) {
            float4 v = h1j[q];
            h1r[4 * q] = v.x; h1r[4 * q + 1] = v.y; h1r[4 * q + 2] = v.z; h1r[4 * q + 3] = v.w;
        }
#pragma unroll
        for (int i = 0; i < 8; ++i) {
            const float4* hp = (const float4*)(hos + i * 32);
            float acc = 0.f;
#pragma unroll
            for (int q = 0; q < 8; ++q) {
                float4 hv = hp[q];
                acc = fmaf(tanh_fast(hv.x + h1r[4 * q]), wpr[4 * q], acc);
                acc = fmaf(tanh_fast(hv.y + h1r[4 * q + 1]), wpr[4 * q + 1], acc);
                acc = fmaf(tanh_fast(hv.z + h1r[4 * q + 2]), wpr[4 * q + 2], acc);
                acc = fmaf(tanh_fast(hv.w + h1r[4 * q + 3]), wpr[4 * q + 3], acc);
            }
            S[((size_t)b * Nc + i0 + i) * Nc + j] = acc;
        }
    }
}

// K2: one wave per (b,i): softmax row (in-place S -> alpha), ctx[b,i,k] = sum_j alpha*e (recompute e).
__global__ __launch_bounds__(64) void softmax_ctx(
        float* __restrict__ S, const float* __restrict__ ho, const float* __restrict__ h1,
        float* __restrict__ ctx) {
    int bi = blockIdx.x;
    int b = bi >> 9;
    int t = threadIdx.x;  // 64
    __shared__ float als[Nc];
    float* Sr = S + (size_t)bi * Nc;
    float4 s0 = ((const float4*)Sr)[t];
    float4 s1 = ((const float4*)Sr)[t + 64];
    float m = fmaxf(fmaxf(fmaxf(s0.x, s0.y), fmaxf(s0.z, s0.w)),
                    fmaxf(fmaxf(s1.x, s1.y), fmaxf(s1.z, s1.w)));
#pragma unroll
    for (int o = 32; o > 0; o >>= 1) m = fmaxf(m, __shfl_xor(m, o));
    float4 e0, e1;
    e0.x = __expf(s0.x - m); e0.y = __expf(s0.y - m); e0.z = __expf(s0.z - m); e0.w = __expf(s0.w - m);
    e1.x = __expf(s1.x - m); e1.y = __expf(s1.y - m); e1.z = __expf(s1.z - m); e1.w = __expf(s1.w - m);
    float sum = e0.x + e0.y + e0.z + e0.w + e1.x + e1.y + e1.z + e1.w;
#pragma unroll
    for (int o = 32; o > 0; o >>= 1) sum += __shfl_xor(sum, o);
    float rinv = 1.f / sum;
    e0.x *= rinv; e0.y *= rinv; e0.z *= rinv; e0.w *= rinv;
    e1.x *= rinv; e1.y *= rinv; e1.z *= rinv; e1.w *= rinv;
    ((float4*)Sr)[t] = e0;
    ((float4*)Sr)[t + 64] = e1;
    ((float4*)als)[t] = e0;
    ((float4*)als)[t + 64] = e1;
    __syncthreads();
    int k = t & 31, g = t >> 5;
    float hok = ho[(size_t)bi * 32 + k];
    const float* h1b = h1 + (size_t)b * Nc * 32;
    float c = 0.f;
    for (int j = g; j < Nc; j += 2)
        c = fmaf(als[j], tanh_fast(hok + h1b[(size_t)j * 32 + k]), c);
    c += __shfl_down(c, 32);
    if (t < 32) ctx[(size_t)bi * 32 + t] = c;
}

// K3: Xbar = alpha@Xy + We·ctx + we_b + XA + XAC.  grid = B*(N/8), 256 threads.
// thread = (i_loc = t>>5 in 0..7, h4 = (t&31)*4), owns float4 of output over full j.
__global__ __launch_bounds__(256) void attn_out(
        const float* __restrict__ alpha, const float* __restrict__ Xy,
        const float* __restrict__ ctx, const float* __restrict__ we_w,
        const float* __restrict__ we_b, const float* __restrict__ XA,
        const float* __restrict__ XAC, float* __restrict__ Xbar) {
    int blk = blockIdx.x;
    int b = blk >> 6;
    int i0 = (blk & 63) * 8;
    int t = threadIdx.x;
    __shared__ float als[8 * Nc];
    __shared__ float ctxs[8 * 32];
    {
        const float4* ap = (const float4*)(alpha + ((size_t)b * Nc + i0) * Nc);
#pragma unroll
        for (int q = 0; q < 4; ++q) ((float4*)als)[t + q * 256] = ap[t + q * 256];
        ctxs[t] = ctx[((size_t)b * Nc + i0) * 32 + t];
    }
    __syncthreads();
    int i_loc = t >> 5;
    int h4 = (t & 31) * 4;
    const float* Xyb = Xy + (size_t)b * Nc * Hc;
    const float* al = als + i_loc * Nc;
    float4 acc = make_float4(0.f, 0.f, 0.f, 0.f);
    for (int j = 0; j < Nc; j += 2) {
        float2 av = *(const float2*)(al + j);
        float4 x0 = *(const float4*)(Xyb + (size_t)j * Hc + h4);
        float4 x1 = *(const float4*)(Xyb + (size_t)(j + 1) * Hc + h4);
        acc.x = fmaf(av.x, x0.x, acc.x); acc.y = fmaf(av.x, x0.y, acc.y);
        acc.z = fmaf(av.x, x0.z, acc.z); acc.w = fmaf(av.x, x0.w, acc.w);
        acc.x = fmaf(av.y, x1.x, acc.x); acc.y = fmaf(av.y, x1.y, acc.y);
        acc.z = fmaf(av.y, x1.z, acc.z); acc.w = fmaf(av.y, x1.w, acc.w);
    }
    // epilogue: We·ctx + we_b
    const float4* crow = (const float4*)(ctxs + i_loc * 32);
    float4 wb = *(const float4*)(we_b + h4);
    float wec[4];
#pragma unroll
    for (int ho_ = 0; ho_ < 4; ++ho_) {
        const float4* wrow = (const float4*)(we_w + (size_t)(h4 + ho_) * 32);
        float s = 0.f;
#pragma unroll
        for (int q = 0; q < 8; ++q) {
            float4 w4 = wrow[q];
            float4 c4 = crow[q];
            s = fmaf(w4.x, c4.x, s); s = fmaf(w4.y, c4.y, s);
            s = fmaf(w4.z, c4.z, s); s = fmaf(w4.w, c4.w, s);
        }
        wec[ho_] = s;
    }
    size_t o = ((size_t)b * Nc + i0 + i_loc) * Hc + h4;
    float4 g1 = *(const float4*)(XA + o);
    float4 g2 = *(const float4*)(XAC + o);
    float4 outv;
    outv.x = acc.x + wec[0] + wb.x + g1.x + g2.x;
    outv.y = acc.y + wec[1] + wb.y + g1.y + g2.y;
    outv.z = acc.z + wec[2] + wb.z + g1.z + g2.z;
    outv.w = acc.w + wec[3] + wb.w + g1.w + g2.w;
    *(float4*)(Xbar + o) = outv;
}

// partial row-sum for SE: grid B*8, 128 threads
__global__ __launch_bounds__(128) void rowsum_partial(const float* __restrict__ Xbar, float* __restrict__ P) {
    int blk = blockIdx.x;
    int b = blk >> 3, p = blk & 7;
    int t = threadIdx.x;
    const float* Xb = Xbar + ((size_t)b * Nc + p * 64) * Hc;
    float acc = 0.f;
    for (int i = 0; i < 64; ++i) acc += Xb[(size_t)i * Hc + t];
    P[(size_t)blk * Hc + t] = acc;
}

// grid = B, 128 threads: y2[b,h] = sigmoid(lin2(relu(lin1(sum_i Xbar))))
__global__ __launch_bounds__(128) void se_kernel(const float* __restrict__ P, const float* __restrict__ l1w,
                          const float* __restrict__ l1b, const float* __restrict__ l2w,
                          const float* __restrict__ l2b, float* __restrict__ y2) {
    int b = blockIdx.x;
    int t = threadIdx.x; // 128
    __shared__ float s[Hc];
    __shared__ float y1s[REDc];
    float acc = 0.f;
#pragma unroll
    for (int p = 0; p < 8; ++p) acc += P[((size_t)b * 8 + p) * Hc + t];
    s[t] = acc;
    __syncthreads();
    if (t < REDc) {
        float a = l1b[t];
        const float* w = l1w + (size_t)t * Hc;
        for (int k = 0; k < Hc; ++k) a = fmaf(s[k], w[k], a);
        y1s[t] = fmaxf(a, 0.f);
    }
    __syncthreads();
    float a = l2b[t];
    const float* w2 = l2w + (size_t)t * REDc;
#pragma unroll
    for (int k = 0; k < REDc; ++k) a = fmaf(y1s[k], w2[k], a);
    y2[(size_t)b * Hc + t] = 1.f / (1.f + __expf(-a));
}

// grid = B*N, 64 threads: head1(relu) + head2 fused
__global__ __launch_bounds__(64) void head_kernel(const float* __restrict__ Xp, const float* __restrict__ h1w,
                            const float* __restrict__ h1b, const float* __restrict__ h2w,
                            const float* __restrict__ h2b, float* __restrict__ out) {
    int m = blockIdx.x;
    int t = threadIdx.x; // 64
    __shared__ float xs[Hc];
    __shared__ float hs[64];
    xs[t] = Xp[(size_t)m * Hc + t];
    xs[t + 64] = Xp[(size_t)m * Hc + t + 64];
    __syncthreads();
    float a = h1b[t];
    const float* w = h1w + (size_t)t * Hc;
    for (int k = 0; k < Hc; ++k) a = fmaf(xs[k], w[k], a);
    hs[t] = fmaxf(a, 0.f);
    __syncthreads();
    if (t < OUTc) {
        float o = h2b[t];
        const float* w2 = h2w + (size_t)t * 64;
#pragma unroll
        for (int k = 0; k < 64; ++k) o = fmaf(hs[k], w2[k], o);
        out[(size_t)m * OUTc + t] = o;
    }
}

extern "C" void kernel_launch(void* const* d_in, const int* in_sizes, int n_in,
                              void* d_out, int out_size, void* d_ws, size_t ws_size,
                              hipStream_t stream) {
    const float* X       = (const float*)d_in[0];
    const float* A       = (const float*)d_in[1];
    const float* Acg     = (const float*)d_in[2];
    const float* embed_w = (const float*)d_in[3];
    const float* embed_b = (const float*)d_in[4];
    const float* topo_eps= (const float*)d_in[5];
    const float* topo_w  = (const float*)d_in[6];
    const float* topo_b  = (const float*)d_in[7];
    const float* theta   = (const float*)d_in[8];
    const float* gin_eps = (const float*)d_in[9];
    const float* gin_w   = (const float*)d_in[10];
    const float* gin_b   = (const float*)d_in[11];
    const float* wo      = (const float*)d_in[12];
    const float* w1      = (const float*)d_in[13];
    const float* wphi    = (const float*)d_in[14];
    const float* wy_w    = (const float*)d_in[15];
    const float* wy_b    = (const float*)d_in[16];
    const float* we_w    = (const float*)d_in[17];
    const float* we_b    = (const float*)d_in[18];
    const float* lin1_w  = (const float*)d_in[19];
    const float* lin1_b  = (const float*)d_in[20];
    const float* lin2_w  = (const float*)d_in[21];
    const float* lin2_b  = (const float*)d_in[22];
    const float* mlp_w   = (const float*)d_in[23];
    const float* mlp_b   = (const float*)d_in[24];
    const float* head1_w = (const float*)d_in[25];
    const float* head1_b = (const float*)d_in[26];
    const float* head2_w = (const float*)d_in[27];
    const float* head2_b = (const float*)d_in[28];
    float* out = (float*)d_out;

    float* ws = (float*)d_ws;
    const int MN = Bc * Nc;              // 4096
    const size_t SZ = (size_t)MN * Hc;   // 524288
    float* Xh   = ws;
    float* Xp   = Xh + SZ;
    float* T    = Xp + SZ;
    float* G1   = T + SZ;
    float* G2   = G1 + SZ;
    float* Xy   = G2 + SZ;
    float* Xbar = Xy + SZ;
    float* S    = Xbar + SZ;                       // B*N*N = 2M floats (alpha in-place)
    float* hov  = S + (size_t)Bc * Nc * Nc;        // MN*32
    float* h1v  = hov + (size_t)MN * Atc;
    float* ctx  = h1v + (size_t)MN * Atc;          // MN*32
    float* y2   = ctx + (size_t)MN * Atc;          // B*H
    float* P    = y2 + (size_t)Bc * Hc;            // B*8*H

    // embed: Xh = X @ embed_w.T + b
    gemm_tm<8, 128><<<MN / 8, 128, 0, stream>>>(X, embed_w, embed_b, Xh, INc, 0, nullptr);
    // topo GIN on A and Ac
    spmm_eps<<<MN, 128, 0, stream>>>(A, Xh, topo_eps, T);
    gemm_tm<8, 128><<<MN / 8, 128, 0, stream>>>(T, topo_w, topo_b, G1, Hc, 1, nullptr);
    spmm_eps<<<MN, 128, 0, stream>>>(Acg, Xh, topo_eps, T);
    gemm_tm<8, 128><<<MN / 8, 128, 0, stream>>>(T, topo_w, topo_b, G2, Hc, 1, nullptr);
    topo_combine<<<(MN * Hc + 255) / 256, 256, 0, stream>>>(Xh, G1, G2, theta, Xp);

    for (int l = 0; l < Lc; ++l) {
        spmm_eps<<<MN, 128, 0, stream>>>(A, Xp, gin_eps + l * 2 + 0, T);
        gemm_tm<8, 128><<<MN / 8, 128, 0, stream>>>(T, gin_w + (size_t)(l * 2 + 0) * Hc * Hc,
                                                    gin_b + (size_t)(l * 2 + 0) * Hc, G1, Hc, 1, nullptr);
        spmm_eps<<<MN, 128, 0, stream>>>(Acg, Xp, gin_eps + l * 2 + 1, T);
        gemm_tm<8, 128><<<MN / 8, 128, 0, stream>>>(T, gin_w + (size_t)(l * 2 + 1) * Hc * Hc,
                                                    gin_b + (size_t)(l * 2 + 1) * Hc, G2, Hc, 1, nullptr);
        gemm_tm<8, 32><<<MN / 8, 128, 0, stream>>>(Xp, wo + (size_t)l * Atc * Hc, nullptr, hov, Hc, 0, nullptr);
        gemm_tm<8, 32><<<MN / 8, 128, 0, stream>>>(Xp, w1 + (size_t)l * Atc * Hc, nullptr, h1v, Hc, 0, nullptr);
        gemm_tm<8, 128><<<MN / 8, 128, 0, stream>>>(Xp, wy_w + (size_t)l * Hc * Hc, wy_b + (size_t)l * Hc, Xy, Hc, 0, nullptr);
        score_kernel<<<MN / 8, 256, 0, stream>>>(hov, h1v, wphi + (size_t)l * Atc, S);
        softmax_ctx<<<MN, 64, 0, stream>>>(S, hov, h1v, ctx);
        attn_out<<<MN / 8, 256, 0, stream>>>(S, Xy, ctx, we_w + (size_t)l * Hc * Atc,
                                             we_b + (size_t)l * Hc, G1, G2, Xbar);
        rowsum_partial<<<Bc * 8, 128, 0, stream>>>(Xbar, P);
        se_kernel<<<Bc, 128, 0, stream>>>(P, lin1_w + (size_t)l * REDc * Hc, lin1_b + (size_t)l * REDc,
                                          lin2_w + (size_t)l * Hc * REDc, lin2_b + (size_t)l * Hc, y2);
        gemm_tm<8, 128><<<MN / 8, 128, 0, stream>>>(Xbar, mlp_w + (size_t)l * Hc * Hc, mlp_b + (size_t)l * Hc, Xp, Hc, 0, y2);
    }
    head_kernel<<<MN, 64, 0, stream>>>(Xp, head1_w, head1_b, head2_w, head2_b, out);
}